// Round 1
// baseline (713.686 us; speedup 1.0000x reference)
//
#include <hip/hip_runtime.h>
#include <math.h>

#define N_NODES 50000
#define IN_F    128
#define OUT_F   128
#define NH      3
#define ED_F    16
#define NE      800000
#define NE2     (NE + N_NODES)
#define HO      (NH * OUT_F)   // 384
#define NEG_SLOPE 0.2f
#define LN_EPS    1e-5f

// ---------------------------------------------------------------------------
// K1: per-dst degree + sum of incoming edge_attr (for self-loop fill 'mean')
// one thread per (edge, dim): coalesced reads, scattered atomics
// ---------------------------------------------------------------------------
__global__ void k_edge_stats(const int* __restrict__ ei, const float* __restrict__ ea,
                             int* __restrict__ deg, float* __restrict__ loopsum)
{
    int gid = blockIdx.x * blockDim.x + threadIdx.x;
    if (gid >= NE * ED_F) return;
    int e = gid >> 4, d = gid & 15;
    int c = ei[NE + e];
    atomicAdd(&loopsum[c * ED_F + d], ea[e * ED_F + d]);
    if (d == 0) atomicAdd(&deg[c], 1);
}

// ---------------------------------------------------------------------------
// K2: tiny precompute:  Wa_src[k,h] = sum_c W[k,h*128+c]*att_src[h,c]   (128x3)
//                       Wa_dst likewise, We[d,h] from W_edge/att_edge   (16x3)
// layout in 'small': [0,384) Wa_src(k*3+h) | [384,768) Wa_dst | [768,816) We
// ---------------------------------------------------------------------------
__global__ void k_small(const float* __restrict__ W, const float* __restrict__ Wed,
                        const float* __restrict__ a_s, const float* __restrict__ a_d,
                        const float* __restrict__ a_e, float* __restrict__ small)
{
    int t = threadIdx.x;
    if (t < 384) {
        int k = t / 3, h = t - k * 3;
        float s1 = 0.f, s2 = 0.f;
        for (int c = 0; c < OUT_F; ++c) {
            float w = W[k * HO + h * OUT_F + c];
            s1 += w * a_s[h * OUT_F + c];
            s2 += w * a_d[h * OUT_F + c];
        }
        small[t] = s1;
        small[384 + t] = s2;
    } else if (t < 384 + 48) {
        int u = t - 384; int d = u / 3, h = u - d * 3;
        float s = 0.f;
        for (int c = 0; c < OUT_F; ++c)
            s += Wed[d * HO + h * OUT_F + c] * a_e[h * OUT_F + c];
        small[768 + u] = s;
    }
}

// ---------------------------------------------------------------------------
// K3: a_src[n,h], a_dst[n,h] = x[n,:] . Wa[:,h]   — one wave per node
// ---------------------------------------------------------------------------
__global__ void k_attn_node(const float* __restrict__ x, const float* __restrict__ small,
                            float* __restrict__ asrc, float* __restrict__ adst)
{
    int n = blockIdx.x * 4 + (threadIdx.x >> 6);
    int l = threadIdx.x & 63;
    if (n >= N_NODES) return;
    float x0 = x[(size_t)n * IN_F + l];
    float x1 = x[(size_t)n * IN_F + 64 + l];
    #pragma unroll
    for (int h = 0; h < 3; ++h) {
        float p = x0 * small[l * 3 + h]        + x1 * small[(64 + l) * 3 + h];
        float q = x0 * small[384 + l * 3 + h]  + x1 * small[384 + (64 + l) * 3 + h];
        #pragma unroll
        for (int s = 32; s; s >>= 1) { p += __shfl_xor(p, s); q += __shfl_xor(q, s); }
        if (l == 0) { asrc[n * 3 + h] = p; adst[n * 3 + h] = q; }
    }
}

// ---------------------------------------------------------------------------
// K_scan: offsets = exclusive scan of (deg[i]+1), single block, wave-scan based
// ---------------------------------------------------------------------------
__global__ void k_scan(const int* __restrict__ deg, int* __restrict__ offs, int n)
{
    __shared__ int wsum[16];
    __shared__ int carry_s;
    int tid = threadIdx.x, lane = tid & 63, w = tid >> 6;
    if (tid == 0) { carry_s = 0; offs[0] = 0; }
    __syncthreads();
    for (int base = 0; base < n; base += 1024) {
        int i = base + tid;
        int v = (i < n) ? deg[i] + 1 : 0;
        int x = v;
        #pragma unroll
        for (int s = 1; s < 64; s <<= 1) {
            int t = __shfl_up(x, s);
            if (lane >= s) x += t;
        }
        if (lane == 63) wsum[w] = x;
        __syncthreads();
        if (w == 0) {
            int t = (lane < 16) ? wsum[lane] : 0;
            #pragma unroll
            for (int s = 1; s < 16; s <<= 1) {
                int u = __shfl_up(t, s);
                if (lane >= s) t += u;
            }
            if (lane < 16) wsum[lane] = t;
        }
        __syncthreads();
        int wpref = (w > 0) ? wsum[w - 1] : 0;
        int incl = carry_s + wpref + x;
        if (i < n) offs[i + 1] = incl;
        __syncthreads();
        if (tid == 1023) carry_s += wsum[15];
        __syncthreads();
    }
}

// ---------------------------------------------------------------------------
// K4: per-edge alpha (leaky) + CSR fill (bucket edge ids by destination)
// ---------------------------------------------------------------------------
__global__ void k_alpha_fill(const int* __restrict__ ei, const float* __restrict__ ea,
                             const int* __restrict__ deg, const float* __restrict__ loopsum,
                             const float* __restrict__ small,
                             const float* __restrict__ asrc, const float* __restrict__ adst,
                             const int* __restrict__ offs, int* __restrict__ cursor,
                             int* __restrict__ eidb, float* __restrict__ alpha)
{
    int e = blockIdx.x * blockDim.x + threadIdx.x;
    if (e >= NE2) return;
    int r, c;
    float v[16];
    if (e < NE) {
        r = ei[e]; c = ei[NE + e];
        const float4* p = (const float4*)(ea + (size_t)e * 16);
        float4 q0 = p[0], q1 = p[1], q2 = p[2], q3 = p[3];
        v[0]=q0.x; v[1]=q0.y; v[2]=q0.z; v[3]=q0.w;
        v[4]=q1.x; v[5]=q1.y; v[6]=q1.z; v[7]=q1.w;
        v[8]=q2.x; v[9]=q2.y; v[10]=q2.z; v[11]=q2.w;
        v[12]=q3.x; v[13]=q3.y; v[14]=q3.z; v[15]=q3.w;
    } else {
        int i = e - NE; r = c = i;
        float inv = 1.0f / fmaxf((float)deg[i], 1.0f);
        #pragma unroll
        for (int d = 0; d < 16; ++d) v[d] = loopsum[i * 16 + d] * inv;
    }
    const float* Wev = small + 768;
    #pragma unroll
    for (int h = 0; h < 3; ++h) {
        float ae = 0.f;
        #pragma unroll
        for (int d = 0; d < 16; ++d) ae += v[d] * Wev[d * 3 + h];
        float al = asrc[r * 3 + h] + adst[c * 3 + h] + ae;
        alpha[(size_t)e * 3 + h] = (al >= 0.f) ? al : NEG_SLOPE * al;
    }
    int pos = atomicAdd(&cursor[c], 1);
    eidb[offs[c] + pos] = e;
}

// ---------------------------------------------------------------------------
// K6: per-dst-node block: segment softmax (3 phases, no atomics) + weighted
// gather of xp rows -> x_gat.  128 threads: thread t holds element t of all
// 3 heads (offsets t, 128+t, 256+t).
// ---------------------------------------------------------------------------
__global__ __launch_bounds__(128)
void k_aggregate(const int* __restrict__ ei, const int* __restrict__ offs,
                 const int* __restrict__ eidb, const float* __restrict__ alpha,
                 const float* __restrict__ xp, const float* __restrict__ gbias,
                 float* __restrict__ xgat)
{
    int n = blockIdx.x;
    int t = threadIdx.x;
    int off = offs[n], ne = offs[n + 1] - off;

    float m0 = -3.4e38f, m1 = -3.4e38f, m2 = -3.4e38f;
    for (int i = 0; i < ne; ++i) {
        int e = eidb[off + i];
        m0 = fmaxf(m0, alpha[(size_t)e * 3 + 0]);
        m1 = fmaxf(m1, alpha[(size_t)e * 3 + 1]);
        m2 = fmaxf(m2, alpha[(size_t)e * 3 + 2]);
    }
    float s0 = 0.f, s1 = 0.f, s2 = 0.f;
    for (int i = 0; i < ne; ++i) {
        int e = eidb[off + i];
        s0 += __expf(alpha[(size_t)e * 3 + 0] - m0);
        s1 += __expf(alpha[(size_t)e * 3 + 1] - m1);
        s2 += __expf(alpha[(size_t)e * 3 + 2] - m2);
    }
    float i0 = 1.f / s0, i1 = 1.f / s1, i2 = 1.f / s2;

    float a0 = 0.f, a1 = 0.f, a2 = 0.f;
    for (int i = 0; i < ne; ++i) {
        int e = eidb[off + i];
        int r = (e < NE) ? ei[e] : n;
        float w0 = __expf(alpha[(size_t)e * 3 + 0] - m0) * i0;
        float w1 = __expf(alpha[(size_t)e * 3 + 1] - m1) * i1;
        float w2 = __expf(alpha[(size_t)e * 3 + 2] - m2) * i2;
        const float* xr = xp + (size_t)r * HO;
        a0 += w0 * xr[t];
        a1 += w1 * xr[128 + t];
        a2 += w2 * xr[256 + t];
    }
    size_t b = (size_t)n * HO;
    xgat[b + t]       = a0 + gbias[t];
    xgat[b + 128 + t] = a1 + gbias[128 + t];
    xgat[b + 256 + t] = a2 + gbias[256 + t];
}

// ---------------------------------------------------------------------------
// Tiled fp32 GEMM: C[M,N] = A[M,K] @ B[K,N]  (BM=64, BN=64, BK=32, 4x4/thread)
// EPI==1: C = A@B + bias[col] + resid[row,col]   (N == resid ld == 128)
// ---------------------------------------------------------------------------
template<int EPI>
__global__ __launch_bounds__(256)
void k_gemm(const float* __restrict__ A, const float* __restrict__ B,
            float* __restrict__ C, int M, int N, int K,
            const float* __restrict__ bias, const float* __restrict__ resid)
{
    __shared__ float As[32][68];  // [k][m], 68*4B row = 272B (16B aligned rows)
    __shared__ float Bs[32][68];  // [k][n]
    int bm = blockIdx.x * 64, bn = blockIdx.y * 64;
    int tid = threadIdx.x;
    int tr = tid >> 4, tc = tid & 15;
    float acc[4][4] = {};

    for (int k0 = 0; k0 < K; k0 += 32) {
        #pragma unroll
        for (int it = 0; it < 2; ++it) {
            int r  = (tid >> 3) + it * 32;      // 0..63
            int c4 = (tid & 7) * 4;             // 0..28
            int gr = bm + r;
            float4 v = make_float4(0.f, 0.f, 0.f, 0.f);
            if (gr < M) v = *(const float4*)&A[(size_t)gr * K + k0 + c4];
            As[c4 + 0][r] = v.x; As[c4 + 1][r] = v.y;
            As[c4 + 2][r] = v.z; As[c4 + 3][r] = v.w;
        }
        #pragma unroll
        for (int it = 0; it < 2; ++it) {
            int kr = (tid >> 4) + it * 16;      // 0..31
            int c4 = (tid & 15) * 4;            // 0..60
            float4 v = *(const float4*)&B[(size_t)(k0 + kr) * N + bn + c4];
            *(float4*)&Bs[kr][c4] = v;
        }
        __syncthreads();
        #pragma unroll
        for (int kk = 0; kk < 32; ++kk) {
            float4 a = *(float4*)&As[kk][tr * 4];
            float4 b = *(float4*)&Bs[kk][tc * 4];
            float av[4] = {a.x, a.y, a.z, a.w};
            float bv[4] = {b.x, b.y, b.z, b.w};
            #pragma unroll
            for (int i = 0; i < 4; ++i)
                #pragma unroll
                for (int j = 0; j < 4; ++j)
                    acc[i][j] += av[i] * bv[j];
        }
        __syncthreads();
    }
    #pragma unroll
    for (int i = 0; i < 4; ++i) {
        int gr = bm + tr * 4 + i;
        if (gr < M) {
            int gc = bn + tc * 4;
            float4 o = make_float4(acc[i][0], acc[i][1], acc[i][2], acc[i][3]);
            if (EPI) {
                size_t rb = (size_t)gr * N + gc;
                o.x += bias[gc + 0] + resid[rb + 0];
                o.y += bias[gc + 1] + resid[rb + 1];
                o.z += bias[gc + 2] + resid[rb + 2];
                o.w += bias[gc + 3] + resid[rb + 3];
            }
            *(float4*)&C[(size_t)gr * N + gc] = o;
        }
    }
}

// ---------------------------------------------------------------------------
// K9: LayerNorm over last dim (128), one wave per row
// ---------------------------------------------------------------------------
__global__ void k_ln(const float* __restrict__ h, const float* __restrict__ g,
                     const float* __restrict__ b, float* __restrict__ out)
{
    int n = blockIdx.x * 4 + (threadIdx.x >> 6);
    int l = threadIdx.x & 63;
    if (n >= N_NODES) return;
    size_t base = (size_t)n * 128;
    float h0 = h[base + l], h1 = h[base + 64 + l];
    float s = h0 + h1;
    #pragma unroll
    for (int k = 32; k; k >>= 1) s += __shfl_xor(s, k);
    float mu = s * (1.0f / 128.0f);
    float d0 = h0 - mu, d1 = h1 - mu;
    float v = d0 * d0 + d1 * d1;
    #pragma unroll
    for (int k = 32; k; k >>= 1) v += __shfl_xor(v, k);
    float rs = rsqrtf(v * (1.0f / 128.0f) + LN_EPS);
    out[base + l]      = d0 * rs * g[l]      + b[l];
    out[base + 64 + l] = d1 * rs * g[64 + l] + b[64 + l];
}

// ---------------------------------------------------------------------------
extern "C" void kernel_launch(void* const* d_in, const int* in_sizes, int n_in,
                              void* d_out, int out_size, void* d_ws, size_t ws_size,
                              hipStream_t stream)
{
    const float* x    = (const float*)d_in[0];
    const int*   ei   = (const int*)  d_in[1];
    const float* ea   = (const float*)d_in[2];
    const float* W    = (const float*)d_in[3];
    const float* Wed  = (const float*)d_in[4];
    const float* asv  = (const float*)d_in[5];
    const float* adv  = (const float*)d_in[6];
    const float* aev  = (const float*)d_in[7];
    const float* gb   = (const float*)d_in[8];
    const float* lw   = (const float*)d_in[9];
    const float* lb   = (const float*)d_in[10];
    const float* lng  = (const float*)d_in[11];
    const float* lnb  = (const float*)d_in[12];
    float* out = (float*)d_out;

    char* wsp = (char*)d_ws;
    size_t off = 0;
    auto alloc = [&](size_t bytes) -> void* {
        void* p = wsp + off;
        off += bytes;
        off = (off + 255) & ~(size_t)255;
        return p;
    };

    // zero-init region first (deg, cursor, loopsum must be contiguous at start)
    int*   deg     = (int*)  alloc((size_t)N_NODES * 4);
    int*   cursor  = (int*)  alloc((size_t)N_NODES * 4);
    float* loopsum = (float*)alloc((size_t)N_NODES * ED_F * 4);
    size_t zero_bytes = off;
    float* small   = (float*)alloc(816 * 4);
    float* asrc    = (float*)alloc((size_t)N_NODES * 3 * 4);
    float* adst    = (float*)alloc((size_t)N_NODES * 3 * 4);
    int*   offs    = (int*)  alloc((size_t)(N_NODES + 1) * 4);
    int*   eidb    = (int*)  alloc((size_t)NE2 * 4);
    float* alpha   = (float*)alloc((size_t)NE2 * 3 * 4);
    float* xp      = (float*)alloc((size_t)N_NODES * HO * 4);
    float* xgat    = (float*)alloc((size_t)N_NODES * HO * 4);
    float* hbuf    = (float*)alloc((size_t)N_NODES * OUT_F * 4);
    (void)ws_size; (void)in_sizes; (void)n_in; (void)out_size;

    hipMemsetAsync(d_ws, 0, zero_bytes, stream);

    k_small<<<1, 448, 0, stream>>>(W, Wed, asv, adv, aev, small);
    k_edge_stats<<<(NE * ED_F + 255) / 256, 256, 0, stream>>>(ei, ea, deg, loopsum);
    k_attn_node<<<(N_NODES + 3) / 4, 256, 0, stream>>>(x, small, asrc, adst);
    k_gemm<0><<<dim3((N_NODES + 63) / 64, HO / 64), 256, 0, stream>>>(
        x, W, xp, N_NODES, HO, IN_F, nullptr, nullptr);
    k_scan<<<1, 1024, 0, stream>>>(deg, offs, N_NODES);
    k_alpha_fill<<<(NE2 + 255) / 256, 256, 0, stream>>>(
        ei, ea, deg, loopsum, small, asrc, adst, offs, cursor, eidb, alpha);
    k_aggregate<<<N_NODES, 128, 0, stream>>>(ei, offs, eidb, alpha, xp, gb, xgat);
    k_gemm<1><<<dim3((N_NODES + 63) / 64, OUT_F / 64), 256, 0, stream>>>(
        xgat, lw, hbuf, N_NODES, OUT_F, HO, lb, x);
    k_ln<<<(N_NODES + 3) / 4, 256, 0, stream>>>(hbuf, lng, lnb, out);
}

// Round 2
// 522.967 us; speedup vs baseline: 1.3647x; 1.3647x over previous
//
#include <hip/hip_runtime.h>
#include <hip/hip_bf16.h>
#include <math.h>

#define M_NODES 50000
#define IN_F    128
#define OUT_F   128
#define NH      3
#define ED_F    16
#define NE      800000
#define NE2     (NE + M_NODES)
#define HO      (NH * OUT_F)   // 384
#define NEG_SLOPE 0.2f
#define LN_EPS    1e-5f

typedef __attribute__((ext_vector_type(8))) short bf16x8;
typedef __attribute__((ext_vector_type(4))) float f32x4;

__device__ __forceinline__ float b2f(unsigned short u) {
    unsigned int x = ((unsigned int)u) << 16;
    return __uint_as_float(x);
}
__device__ __forceinline__ unsigned short f2b(float f) {
    __hip_bfloat16 h = __float2bfloat16(f);
    return *(unsigned short*)&h;
}

// ---------------------------------------------------------------------------
// K1: per-dst degree + sum of incoming edge_attr (self-loop fill 'mean')
// ---------------------------------------------------------------------------
__global__ void k_edge_stats(const int* __restrict__ ei, const float* __restrict__ ea,
                             int* __restrict__ deg, float* __restrict__ loopsum)
{
    int gid = blockIdx.x * blockDim.x + threadIdx.x;
    if (gid >= NE * ED_F) return;
    int e = gid >> 4, d = gid & 15;
    int c = ei[NE + e];
    atomicAdd(&loopsum[c * ED_F + d], ea[e * ED_F + d]);
    if (d == 0) atomicAdd(&deg[c], 1);
}

// ---------------------------------------------------------------------------
// K2: tiny precompute of folded attention vectors
// small: [0,384) Wa_src(k*3+h) | [384,768) Wa_dst | [768,816) We(d*3+h)
// ---------------------------------------------------------------------------
__global__ void k_small(const float* __restrict__ W, const float* __restrict__ Wed,
                        const float* __restrict__ a_s, const float* __restrict__ a_d,
                        const float* __restrict__ a_e, float* __restrict__ small)
{
    int t = threadIdx.x;
    if (t < 384) {
        int k = t / 3, h = t - k * 3;
        float s1 = 0.f, s2 = 0.f;
        for (int c = 0; c < OUT_F; ++c) {
            float w = W[k * HO + h * OUT_F + c];
            s1 += w * a_s[h * OUT_F + c];
            s2 += w * a_d[h * OUT_F + c];
        }
        small[t] = s1;
        small[384 + t] = s2;
    } else if (t < 384 + 48) {
        int u = t - 384; int d = u / 3, h = u - d * 3;
        float s = 0.f;
        for (int c = 0; c < OUT_F; ++c)
            s += Wed[d * HO + h * OUT_F + c] * a_e[h * OUT_F + c];
        small[768 + u] = s;
    }
}

// ---------------------------------------------------------------------------
// K3: a_src[n,h], a_dst[n,h] = x[n,:] . Wa[:,h]   — one wave per node (fp32)
// ---------------------------------------------------------------------------
__global__ void k_attn_node(const float* __restrict__ x, const float* __restrict__ small,
                            float* __restrict__ asrc, float* __restrict__ adst)
{
    int n = blockIdx.x * 4 + (threadIdx.x >> 6);
    int l = threadIdx.x & 63;
    if (n >= M_NODES) return;
    float x0 = x[(size_t)n * IN_F + l];
    float x1 = x[(size_t)n * IN_F + 64 + l];
    #pragma unroll
    for (int h = 0; h < 3; ++h) {
        float p = x0 * small[l * 3 + h]        + x1 * small[(64 + l) * 3 + h];
        float q = x0 * small[384 + l * 3 + h]  + x1 * small[384 + (64 + l) * 3 + h];
        #pragma unroll
        for (int s = 32; s; s >>= 1) { p += __shfl_xor(p, s); q += __shfl_xor(q, s); }
        if (l == 0) { asrc[n * 3 + h] = p; adst[n * 3 + h] = q; }
    }
}

// ---------------------------------------------------------------------------
// K_scan: offs = exclusive scan of (deg[i]+1), single block
// ---------------------------------------------------------------------------
__global__ void k_scan(const int* __restrict__ deg, int* __restrict__ offs, int n)
{
    __shared__ int wsum[16];
    __shared__ int carry_s;
    int tid = threadIdx.x, lane = tid & 63, w = tid >> 6;
    if (tid == 0) { carry_s = 0; offs[0] = 0; }
    __syncthreads();
    for (int base = 0; base < n; base += 1024) {
        int i = base + tid;
        int v = (i < n) ? deg[i] + 1 : 0;
        int x = v;
        #pragma unroll
        for (int s = 1; s < 64; s <<= 1) {
            int t = __shfl_up(x, s);
            if (lane >= s) x += t;
        }
        if (lane == 63) wsum[w] = x;
        __syncthreads();
        if (w == 0) {
            int t = (lane < 16) ? wsum[lane] : 0;
            #pragma unroll
            for (int s = 1; s < 16; s <<= 1) {
                int u = __shfl_up(t, s);
                if (lane >= s) t += u;
            }
            if (lane < 16) wsum[lane] = t;
        }
        __syncthreads();
        int wpref = (w > 0) ? wsum[w - 1] : 0;
        int incl = carry_s + wpref + x;
        if (i < n) offs[i + 1] = incl;
        __syncthreads();
        if (tid == 1023) carry_s += wsum[15];
        __syncthreads();
    }
}

// ---------------------------------------------------------------------------
// K4: per-edge w = exp(leaky(alpha)), atomic denom, CSR fill
// ---------------------------------------------------------------------------
__global__ void k_alpha_fill(const int* __restrict__ ei, const float* __restrict__ ea,
                             const int* __restrict__ deg, const float* __restrict__ loopsum,
                             const float* __restrict__ small,
                             const float* __restrict__ asrc, const float* __restrict__ adst,
                             const int* __restrict__ offs, int* __restrict__ cursor,
                             int* __restrict__ eidb, float* __restrict__ wbuf,
                             float* __restrict__ denom)
{
    int e = blockIdx.x * blockDim.x + threadIdx.x;
    if (e >= NE2) return;
    int r, c;
    float v[16];
    if (e < NE) {
        r = ei[e]; c = ei[NE + e];
        const float4* p = (const float4*)(ea + (size_t)e * 16);
        float4 q0 = p[0], q1 = p[1], q2 = p[2], q3 = p[3];
        v[0]=q0.x; v[1]=q0.y; v[2]=q0.z; v[3]=q0.w;
        v[4]=q1.x; v[5]=q1.y; v[6]=q1.z; v[7]=q1.w;
        v[8]=q2.x; v[9]=q2.y; v[10]=q2.z; v[11]=q2.w;
        v[12]=q3.x; v[13]=q3.y; v[14]=q3.z; v[15]=q3.w;
    } else {
        int i = e - NE; r = c = i;
        float inv = 1.0f / fmaxf((float)deg[i], 1.0f);
        #pragma unroll
        for (int d = 0; d < 16; ++d) v[d] = loopsum[i * 16 + d] * inv;
    }
    const float* Wev = small + 768;
    #pragma unroll
    for (int h = 0; h < 3; ++h) {
        float ae = 0.f;
        #pragma unroll
        for (int d = 0; d < 16; ++d) ae += v[d] * Wev[d * 3 + h];
        float al = asrc[r * 3 + h] + adst[c * 3 + h] + ae;
        al = (al >= 0.f) ? al : NEG_SLOPE * al;
        float w = __expf(al);
        wbuf[(size_t)e * 3 + h] = w;
        atomicAdd(&denom[c * 3 + h], w);
    }
    int pos = atomicAdd(&cursor[c], 1);
    eidb[offs[c] + pos] = e;
}

// ---------------------------------------------------------------------------
// K6: single-pass weighted gather: xgat[n] = (sum_e w_e * xp[r_e]) / denom + bias
// xp is bf16 (768 B/row gather), accumulate fp32, output bf16
// ---------------------------------------------------------------------------
__global__ __launch_bounds__(128)
void k_aggregate(const int* __restrict__ ei, const int* __restrict__ offs,
                 const int* __restrict__ eidb, const float* __restrict__ wbuf,
                 const float* __restrict__ denom,
                 const unsigned short* __restrict__ xp16,
                 const float* __restrict__ gbias, unsigned short* __restrict__ xgat16)
{
    int n = blockIdx.x;
    int t = threadIdx.x;
    int off = offs[n], ne = offs[n + 1] - off;

    float a0 = 0.f, a1 = 0.f, a2 = 0.f;
    int e = 0, r = 0;
    if (ne > 0) { e = eidb[off]; r = (e < NE) ? ei[e] : n; }
    for (int i = 0; i < ne; ++i) {
        int e2 = 0, r2 = 0;
        if (i + 1 < ne) { e2 = eidb[off + i + 1]; r2 = (e2 < NE) ? ei[e2] : n; }
        float w0 = wbuf[(size_t)e * 3 + 0];
        float w1 = wbuf[(size_t)e * 3 + 1];
        float w2 = wbuf[(size_t)e * 3 + 2];
        const unsigned short* xr = xp16 + (size_t)r * HO;
        a0 += w0 * b2f(xr[t]);
        a1 += w1 * b2f(xr[128 + t]);
        a2 += w2 * b2f(xr[256 + t]);
        e = e2; r = r2;
    }
    float i0 = 1.f / denom[n * 3 + 0];
    float i1 = 1.f / denom[n * 3 + 1];
    float i2 = 1.f / denom[n * 3 + 2];
    size_t b = (size_t)n * HO;
    xgat16[b + t]       = f2b(a0 * i0 + gbias[t]);
    xgat16[b + 128 + t] = f2b(a1 * i1 + gbias[128 + t]);
    xgat16[b + 256 + t] = f2b(a2 * i2 + gbias[256 + t]);
}

// ---------------------------------------------------------------------------
// cast helpers: fp32 -> bf16 (vectorized), fp32 -> bf16 transpose (tiny mats)
// ---------------------------------------------------------------------------
__global__ void k_cast8(const float* __restrict__ in, unsigned short* __restrict__ out, int n8)
{
    int i = blockIdx.x * blockDim.x + threadIdx.x;
    if (i >= n8) return;
    const float4* p = (const float4*)(in + (size_t)i * 8);
    float4 v0 = p[0], v1 = p[1];
    unsigned short u[8];
    u[0]=f2b(v0.x); u[1]=f2b(v0.y); u[2]=f2b(v0.z); u[3]=f2b(v0.w);
    u[4]=f2b(v1.x); u[5]=f2b(v1.y); u[6]=f2b(v1.z); u[7]=f2b(v1.w);
    *(uint4*)(out + (size_t)i * 8) = *(uint4*)u;
}

// out[C][R] (bf16) = transpose(in[R][C])
__global__ void k_tcast(const float* __restrict__ in, unsigned short* __restrict__ out,
                        int R, int C)
{
    int o = blockIdx.x * blockDim.x + threadIdx.x;
    if (o >= R * C) return;
    int r = o % R, c = o / R;
    out[o] = f2b(in[(size_t)r * C + c]);
}

// ---------------------------------------------------------------------------
// MFMA GEMM1: xp16[M][384] = x16[M][128] @ W  (B given transposed: Wt[384][128])
// BM=64 (4 waves x 16 rows), BN=64, full K=128 in 2 x BK=64 LDS tiles
// ---------------------------------------------------------------------------
__global__ __launch_bounds__(256)
void k_mm1(const unsigned short* __restrict__ A, const unsigned short* __restrict__ Bt,
           unsigned short* __restrict__ C)
{
    __shared__ char lds[16384]; // As [0,8192), Bs [8192,16384)
    const int bm = blockIdx.x * 64, bn = blockIdx.y * 64;
    const int tid = threadIdx.x, w = tid >> 6, lane = tid & 63;
    const int lrow = lane & 15, lk = lane >> 4;
    const short z0 = 0;
    f32x4 acc[4];
    #pragma unroll
    for (int f = 0; f < 4; ++f) { acc[f][0]=0.f; acc[f][1]=0.f; acc[f][2]=0.f; acc[f][3]=0.f; }

    for (int k0 = 0; k0 < 128; k0 += 64) {
        #pragma unroll
        for (int it = 0; it < 2; ++it) {
            int c = tid + it * 256;
            int row = c >> 3, o = c & 7;
            int grow = bm + row;
            bf16x8 v = {z0,z0,z0,z0,z0,z0,z0,z0};
            if (grow < M_NODES) v = *(const bf16x8*)(A + (size_t)grow * 128 + k0 + o * 8);
            int b = (row * 128 + o * 16) ^ ((row & 7) << 4);
            *(bf16x8*)(lds + b) = v;
        }
        #pragma unroll
        for (int it = 0; it < 2; ++it) {
            int c = tid + it * 256;
            int row = c >> 3, o = c & 7;
            bf16x8 v = *(const bf16x8*)(Bt + (size_t)(bn + row) * 128 + k0 + o * 8);
            int b = 8192 + ((row * 128 + o * 16) ^ ((row & 7) << 4));
            *(bf16x8*)(lds + b) = v;
        }
        __syncthreads();
        #pragma unroll
        for (int kk = 0; kk < 2; ++kk) {
            int ar = w * 16 + lrow;
            bf16x8 a = *(const bf16x8*)(lds + ((ar * 128 + kk * 64 + lk * 16) ^ ((lrow & 7) << 4)));
            #pragma unroll
            for (int f = 0; f < 4; ++f) {
                int br = 16 * f + lrow;
                bf16x8 bb = *(const bf16x8*)(lds + 8192 + ((br * 128 + kk * 64 + lk * 16) ^ ((lrow & 7) << 4)));
                acc[f] = __builtin_amdgcn_mfma_f32_16x16x32_bf16(a, bb, acc[f], 0, 0, 0);
            }
        }
        __syncthreads();
    }
    #pragma unroll
    for (int f = 0; f < 4; ++f) {
        #pragma unroll
        for (int rg = 0; rg < 4; ++rg) {
            int grow = bm + w * 16 + lk * 4 + rg;
            if (grow < M_NODES)
                C[(size_t)grow * 384 + bn + 16 * f + lrow] = f2b(acc[f][rg]);
        }
    }
}

// ---------------------------------------------------------------------------
// MFMA GEMM2 + bias + residual + LayerNorm fused:
// out[M][128] = LN( xgat16[M][384] @ lin_W + lin_b + x )
// Bt = lin_W transposed: [128][384].  BM=64, BN=128(full), BK=64, 6 k-iters.
// ---------------------------------------------------------------------------
__global__ __launch_bounds__(256)
void k_mm2_ln(const unsigned short* __restrict__ A, const unsigned short* __restrict__ Bt,
              const float* __restrict__ bias, const float* __restrict__ xres,
              const float* __restrict__ lng, const float* __restrict__ lnb,
              float* __restrict__ out)
{
    __shared__ char lds[24576]; // As [0,8192), Bs [8192,24576)
    const int bm = blockIdx.x * 64;
    const int tid = threadIdx.x, w = tid >> 6, lane = tid & 63;
    const int lrow = lane & 15, lk = lane >> 4;
    const short z0 = 0;
    f32x4 acc[8];
    #pragma unroll
    for (int f = 0; f < 8; ++f) { acc[f][0]=0.f; acc[f][1]=0.f; acc[f][2]=0.f; acc[f][3]=0.f; }

    for (int k0 = 0; k0 < 384; k0 += 64) {
        #pragma unroll
        for (int it = 0; it < 2; ++it) {
            int c = tid + it * 256;
            int row = c >> 3, o = c & 7;
            int grow = bm + row;
            bf16x8 v = {z0,z0,z0,z0,z0,z0,z0,z0};
            if (grow < M_NODES) v = *(const bf16x8*)(A + (size_t)grow * 384 + k0 + o * 8);
            int b = (row * 128 + o * 16) ^ ((row & 7) << 4);
            *(bf16x8*)(lds + b) = v;
        }
        #pragma unroll
        for (int it = 0; it < 4; ++it) {
            int c = tid + it * 256;
            int row = c >> 3, o = c & 7;   // row 0..127
            bf16x8 v = *(const bf16x8*)(Bt + (size_t)row * 384 + k0 + o * 8);
            int b = 8192 + ((row * 128 + o * 16) ^ ((row & 7) << 4));
            *(bf16x8*)(lds + b) = v;
        }
        __syncthreads();
        #pragma unroll
        for (int kk = 0; kk < 2; ++kk) {
            int ar = w * 16 + lrow;
            bf16x8 a = *(const bf16x8*)(lds + ((ar * 128 + kk * 64 + lk * 16) ^ ((lrow & 7) << 4)));
            #pragma unroll
            for (int f = 0; f < 8; ++f) {
                int br = 16 * f + lrow;
                bf16x8 bb = *(const bf16x8*)(lds + 8192 + ((br * 128 + kk * 64 + lk * 16) ^ ((lrow & 7) << 4)));
                acc[f] = __builtin_amdgcn_mfma_f32_16x16x32_bf16(a, bb, acc[f], 0, 0, 0);
            }
        }
        __syncthreads();
    }

    // fused bias + residual + LayerNorm epilogue
    int cols[8]; float bs[8], gg[8], bbv[8];
    #pragma unroll
    for (int f = 0; f < 8; ++f) {
        cols[f] = 16 * f + lrow;
        bs[f] = bias[cols[f]];
        gg[f] = lng[cols[f]];
        bbv[f] = lnb[cols[f]];
    }
    #pragma unroll
    for (int rg = 0; rg < 4; ++rg) {
        int grow = bm + w * 16 + lk * 4 + rg;
        bool ok = grow < M_NODES;
        float h[8];
        float s = 0.f;
        #pragma unroll
        for (int f = 0; f < 8; ++f) {
            float hv = 0.f;
            if (ok) hv = acc[f][rg] + bs[f] + xres[(size_t)grow * 128 + cols[f]];
            h[f] = hv;
            s += hv;
        }
        #pragma unroll
        for (int m = 1; m < 16; m <<= 1) s += __shfl_xor(s, m);
        float mu = s * (1.0f / 128.0f);
        float vv = 0.f;
        #pragma unroll
        for (int f = 0; f < 8; ++f) { float d = h[f] - mu; vv += d * d; }
        #pragma unroll
        for (int m = 1; m < 16; m <<= 1) vv += __shfl_xor(vv, m);
        float rs = rsqrtf(vv * (1.0f / 128.0f) + LN_EPS);
        if (ok) {
            #pragma unroll
            for (int f = 0; f < 8; ++f)
                out[(size_t)grow * 128 + cols[f]] = (h[f] - mu) * rs * gg[f] + bbv[f];
        }
    }
}

// ---------------------------------------------------------------------------
extern "C" void kernel_launch(void* const* d_in, const int* in_sizes, int n_in,
                              void* d_out, int out_size, void* d_ws, size_t ws_size,
                              hipStream_t stream)
{
    const float* x    = (const float*)d_in[0];
    const int*   ei   = (const int*)  d_in[1];
    const float* ea   = (const float*)d_in[2];
    const float* W    = (const float*)d_in[3];
    const float* Wed  = (const float*)d_in[4];
    const float* asv  = (const float*)d_in[5];
    const float* adv  = (const float*)d_in[6];
    const float* aev  = (const float*)d_in[7];
    const float* gb   = (const float*)d_in[8];
    const float* lw   = (const float*)d_in[9];
    const float* lb   = (const float*)d_in[10];
    const float* lng  = (const float*)d_in[11];
    const float* lnb  = (const float*)d_in[12];
    float* out = (float*)d_out;

    char* wsp = (char*)d_ws;
    size_t off = 0;
    auto alloc = [&](size_t bytes) -> void* {
        void* p = wsp + off;
        off += bytes;
        off = (off + 255) & ~(size_t)255;
        return p;
    };

    // zero-init region (must be contiguous at start)
    int*   deg     = (int*)  alloc((size_t)M_NODES * 4);
    int*   cursor  = (int*)  alloc((size_t)M_NODES * 4);
    float* loopsum = (float*)alloc((size_t)M_NODES * ED_F * 4);
    float* denom   = (float*)alloc((size_t)M_NODES * 3 * 4);
    size_t zero_bytes = off;
    float* small   = (float*)alloc(816 * 4);
    float* asrc    = (float*)alloc((size_t)M_NODES * 3 * 4);
    float* adst    = (float*)alloc((size_t)M_NODES * 3 * 4);
    int*   offs    = (int*)  alloc((size_t)(M_NODES + 1) * 4);
    int*   eidb    = (int*)  alloc((size_t)NE2 * 4);
    float* wbuf    = (float*)alloc((size_t)NE2 * 3 * 4);
    unsigned short* x16    = (unsigned short*)alloc((size_t)M_NODES * IN_F * 2);
    unsigned short* Wt16   = (unsigned short*)alloc((size_t)HO * IN_F * 2);
    unsigned short* lWt16  = (unsigned short*)alloc((size_t)OUT_F * HO * 2);
    unsigned short* xp16   = (unsigned short*)alloc((size_t)M_NODES * HO * 2);
    unsigned short* xgat16 = (unsigned short*)alloc((size_t)M_NODES * HO * 2);
    (void)ws_size; (void)in_sizes; (void)n_in; (void)out_size;

    hipMemsetAsync(d_ws, 0, zero_bytes, stream);

    k_small<<<1, 448, 0, stream>>>(W, Wed, asv, adv, aev, small);
    k_cast8<<<(M_NODES * IN_F / 8 + 255) / 256, 256, 0, stream>>>(x, x16, M_NODES * IN_F / 8);
    k_tcast<<<(IN_F * HO + 255) / 256, 256, 0, stream>>>(W, Wt16, IN_F, HO);
    k_tcast<<<(HO * OUT_F + 255) / 256, 256, 0, stream>>>(lw, lWt16, HO, OUT_F);
    k_edge_stats<<<(NE * ED_F + 255) / 256, 256, 0, stream>>>(ei, ea, deg, loopsum);
    k_attn_node<<<(M_NODES + 3) / 4, 256, 0, stream>>>(x, small, asrc, adst);
    k_mm1<<<dim3((M_NODES + 63) / 64, HO / 64), 256, 0, stream>>>(x16, Wt16, xp16);
    k_scan<<<1, 1024, 0, stream>>>(deg, offs, M_NODES);
    k_alpha_fill<<<(NE2 + 255) / 256, 256, 0, stream>>>(
        ei, ea, deg, loopsum, small, asrc, adst, offs, cursor, eidb, wbuf, denom);
    k_aggregate<<<M_NODES, 128, 0, stream>>>(ei, offs, eidb, wbuf, denom, xp16, gb, xgat16);
    k_mm2_ln<<<(M_NODES + 63) / 64, 256, 0, stream>>>(xgat16, lWt16, lb, x, lng, lnb, out);
}

// Round 3
// 330.851 us; speedup vs baseline: 2.1571x; 1.5807x over previous
//
#include <hip/hip_runtime.h>
#include <hip/hip_bf16.h>
#include <math.h>

#define M_NODES 50000
#define IN_F    128
#define OUT_F   128
#define NH      3
#define ED_F    16
#define NE      800000
#define HO      (NH * OUT_F)   // 384
#define NEG_SLOPE 0.2f
#define LN_EPS    1e-5f

typedef __attribute__((ext_vector_type(8))) short bf16x8;
typedef __attribute__((ext_vector_type(4))) float f32x4;

__device__ __forceinline__ float b2f(unsigned short u) {
    unsigned int x = ((unsigned int)u) << 16;
    return __uint_as_float(x);
}
__device__ __forceinline__ unsigned short f2b(float f) {
    __hip_bfloat16 h = __float2bfloat16(f);
    return *(unsigned short*)&h;
}

// ---------------------------------------------------------------------------
// K2: tiny precompute of folded attention vectors
// small: [0,384) Wa_src(k*3+h) | [384,768) Wa_dst | [768,816) We(d*3+h)
// ---------------------------------------------------------------------------
__global__ void k_small(const float* __restrict__ W, const float* __restrict__ Wed,
                        const float* __restrict__ a_s, const float* __restrict__ a_d,
                        const float* __restrict__ a_e, float* __restrict__ small)
{
    int t = threadIdx.x;
    if (t < 384) {
        int k = t / 3, h = t - k * 3;
        float s1 = 0.f, s2 = 0.f;
        for (int c = 0; c < OUT_F; ++c) {
            float w = W[k * HO + h * OUT_F + c];
            s1 += w * a_s[h * OUT_F + c];
            s2 += w * a_d[h * OUT_F + c];
        }
        small[t] = s1;
        small[384 + t] = s2;
    } else if (t < 384 + 48) {
        int u = t - 384; int d = u / 3, h = u - d * 3;
        float s = 0.f;
        for (int c = 0; c < OUT_F; ++c)
            s += Wed[d * HO + h * OUT_F + c] * a_e[h * OUT_F + c];
        small[768 + u] = s;
    }
}

// ---------------------------------------------------------------------------
// Kq: Q[h*128+t, j] = sum_c W[t, h*128+c] * lw[h*128+c, j]
// stored transposed bf16: Qt[j*384 + h*128+t].  grid=384 blocks, 128 thr
// ---------------------------------------------------------------------------
__global__ void k_prep_q(const float* __restrict__ W, const float* __restrict__ lw,
                         unsigned short* __restrict__ Qt)
{
    int i = blockIdx.x;           // h*128 + t
    int h = i >> 7, t = i & 127;
    int j = threadIdx.x;
    float s = 0.f;
    const float* wrow = W + (size_t)t * HO + h * 128;
    const float* lcol = lw + (size_t)(h * 128) * 128 + j;
    #pragma unroll 4
    for (int c = 0; c < 128; ++c)
        s += wrow[c] * lcol[(size_t)c * 128];
    Qt[(size_t)j * HO + i] = f2b(s);
}

// b2[j] = lb[j] + sum_i gb[i]*lw[i*128+j]   (1 block, 128 thr)
__global__ void k_bias2(const float* __restrict__ gb, const float* __restrict__ lw,
                        const float* __restrict__ lb, float* __restrict__ b2)
{
    int j = threadIdx.x;
    float s = lb[j];
    for (int i = 0; i < HO; ++i)
        s += gb[i] * lw[(size_t)i * 128 + j];
    b2[j] = s;
}

// ---------------------------------------------------------------------------
// K3: fused: asrc/adst (fp32 reduce) + x -> bf16 cast.  one wave per node
// ---------------------------------------------------------------------------
__global__ void k_attn_node(const float* __restrict__ x, const float* __restrict__ small,
                            float* __restrict__ asrc, float* __restrict__ adst,
                            unsigned short* __restrict__ x16)
{
    int n = blockIdx.x * 4 + (threadIdx.x >> 6);
    int l = threadIdx.x & 63;
    if (n >= M_NODES) return;
    float x0 = x[(size_t)n * IN_F + l];
    float x1 = x[(size_t)n * IN_F + 64 + l];
    x16[(size_t)n * IN_F + l]      = f2b(x0);
    x16[(size_t)n * IN_F + 64 + l] = f2b(x1);
    #pragma unroll
    for (int h = 0; h < 3; ++h) {
        float p = x0 * small[l * 3 + h]        + x1 * small[(64 + l) * 3 + h];
        float q = x0 * small[384 + l * 3 + h]  + x1 * small[384 + (64 + l) * 3 + h];
        #pragma unroll
        for (int s = 32; s; s >>= 1) { p += __shfl_xor(p, s); q += __shfl_xor(q, s); }
        if (l == 0) { asrc[n * 3 + h] = p; adst[n * 3 + h] = q; }
    }
}

// ---------------------------------------------------------------------------
// K_ae: per edge: ae[e,h] = dot(ea[e], We[:,h]) coalesced; deg count
// ---------------------------------------------------------------------------
__global__ void k_ae(const int* __restrict__ ei, const float* __restrict__ ea,
                     const float* __restrict__ small, float* __restrict__ aebuf,
                     int* __restrict__ deg)
{
    int e = blockIdx.x * blockDim.x + threadIdx.x;
    if (e >= NE) return;
    const float4* p = (const float4*)(ea + (size_t)e * 16);
    float4 q0 = p[0], q1 = p[1], q2 = p[2], q3 = p[3];
    float v[16] = {q0.x,q0.y,q0.z,q0.w, q1.x,q1.y,q1.z,q1.w,
                   q2.x,q2.y,q2.z,q2.w, q3.x,q3.y,q3.z,q3.w};
    const float* Wev = small + 768;
    #pragma unroll
    for (int h = 0; h < 3; ++h) {
        float s = 0.f;
        #pragma unroll
        for (int d = 0; d < 16; ++d) s += v[d] * Wev[d * 3 + h];
        aebuf[(size_t)e * 3 + h] = s;
    }
    atomicAdd(&deg[ei[NE + e]], 1);
}

// ---------------------------------------------------------------------------
// K_scan: offs = exclusive scan of deg, single block
// ---------------------------------------------------------------------------
__global__ void k_scan(const int* __restrict__ deg, int* __restrict__ offs, int n)
{
    __shared__ int wsum[16];
    __shared__ int carry_s;
    int tid = threadIdx.x, lane = tid & 63, w = tid >> 6;
    if (tid == 0) { carry_s = 0; offs[0] = 0; }
    __syncthreads();
    for (int base = 0; base < n; base += 1024) {
        int i = base + tid;
        int v = (i < n) ? deg[i] : 0;
        int x = v;
        #pragma unroll
        for (int s = 1; s < 64; s <<= 1) {
            int t = __shfl_up(x, s);
            if (lane >= s) x += t;
        }
        if (lane == 63) wsum[w] = x;
        __syncthreads();
        if (w == 0) {
            int t = (lane < 16) ? wsum[lane] : 0;
            #pragma unroll
            for (int s = 1; s < 16; s <<= 1) {
                int u = __shfl_up(t, s);
                if (lane >= s) t += u;
            }
            if (lane < 16) wsum[lane] = t;
        }
        __syncthreads();
        int wpref = (w > 0) ? wsum[w - 1] : 0;
        int incl = carry_s + wpref + x;
        if (i < n) offs[i + 1] = incl;
        __syncthreads();
        if (tid == 1023) carry_s += wsum[15];
        __syncthreads();
    }
}

// ---------------------------------------------------------------------------
// K_fill: CSR fill with packed 32B records {r, ae0..2, asrc(r)0..2, pad}
// ---------------------------------------------------------------------------
__global__ void k_fill(const int* __restrict__ ei, const float* __restrict__ aebuf,
                       const float* __restrict__ asrc, const int* __restrict__ offs,
                       int* __restrict__ cursor, float4* __restrict__ edata)
{
    int e = blockIdx.x * blockDim.x + threadIdx.x;
    if (e >= NE) return;
    int r = ei[e], c = ei[NE + e];
    float a0 = aebuf[(size_t)e * 3 + 0];
    float a1 = aebuf[(size_t)e * 3 + 1];
    float a2 = aebuf[(size_t)e * 3 + 2];
    float s0 = asrc[r * 3 + 0];
    float s1 = asrc[r * 3 + 1];
    float s2 = asrc[r * 3 + 2];
    int pos = atomicAdd(&cursor[c], 1);
    size_t o = (size_t)(offs[c] + pos) * 2;
    edata[o]     = make_float4(__int_as_float(r), a0, a1, a2);
    edata[o + 1] = make_float4(s0, s1, s2, 0.f);
}

// ---------------------------------------------------------------------------
// K_agg: per dst node: one pass over edges; on-the-fly softmax weights;
// gathers x16 rows (256B = 2 lines); self-loop handled analytically.
// sbar[n, h*128+t] = (sum_e w_eh x[r,t] + w_l x[n,t]) / (sum w + w_l)
// ---------------------------------------------------------------------------
__global__ __launch_bounds__(128)
void k_agg(const int* __restrict__ offs, const float4* __restrict__ edata,
           const float* __restrict__ asrc, const float* __restrict__ adst,
           const unsigned short* __restrict__ x16, unsigned short* __restrict__ sbar)
{
    int n = blockIdx.x;
    int t = threadIdx.x;
    int off = offs[n], ne = offs[n + 1] - off;
    float ad0 = adst[n * 3 + 0], ad1 = adst[n * 3 + 1], ad2 = adst[n * 3 + 2];

    float s0 = 0.f, s1 = 0.f, s2 = 0.f;
    float d0 = 0.f, d1 = 0.f, d2 = 0.f;
    float sa0 = 0.f, sa1 = 0.f, sa2 = 0.f;

    for (int i = 0; i < ne; ++i) {
        float4 m0 = edata[(size_t)(off + i) * 2];
        float4 m1 = edata[(size_t)(off + i) * 2 + 1];
        int r = __float_as_int(m0.x);
        float al0 = m1.x + ad0 + m0.y;
        float al1 = m1.y + ad1 + m0.z;
        float al2 = m1.z + ad2 + m0.w;
        al0 = (al0 >= 0.f) ? al0 : NEG_SLOPE * al0;
        al1 = (al1 >= 0.f) ? al1 : NEG_SLOPE * al1;
        al2 = (al2 >= 0.f) ? al2 : NEG_SLOPE * al2;
        float w0 = __expf(al0), w1 = __expf(al1), w2 = __expf(al2);
        sa0 += m0.y; sa1 += m0.z; sa2 += m0.w;
        d0 += w0; d1 += w1; d2 += w2;
        float xv = b2f(x16[(size_t)r * IN_F + t]);
        s0 += w0 * xv; s1 += w1 * xv; s2 += w2 * xv;
    }
    // self-loop: attr = mean of incoming -> ae_loop = mean of ae
    float inv = 1.0f / fmaxf((float)ne, 1.0f);
    float al0 = asrc[n * 3 + 0] + ad0 + sa0 * inv;
    float al1 = asrc[n * 3 + 1] + ad1 + sa1 * inv;
    float al2 = asrc[n * 3 + 2] + ad2 + sa2 * inv;
    al0 = (al0 >= 0.f) ? al0 : NEG_SLOPE * al0;
    al1 = (al1 >= 0.f) ? al1 : NEG_SLOPE * al1;
    al2 = (al2 >= 0.f) ? al2 : NEG_SLOPE * al2;
    float w0 = __expf(al0), w1 = __expf(al1), w2 = __expf(al2);
    float xv = b2f(x16[(size_t)n * IN_F + t]);
    s0 += w0 * xv; s1 += w1 * xv; s2 += w2 * xv;
    d0 += w0; d1 += w1; d2 += w2;

    size_t b = (size_t)n * HO;
    sbar[b + t]       = f2b(s0 / d0);
    sbar[b + 128 + t] = f2b(s1 / d1);
    sbar[b + 256 + t] = f2b(s2 / d2);
}

// ---------------------------------------------------------------------------
// MFMA GEMM + bias + residual + LayerNorm fused:
// out[M][128] = LN( sbar[M][384] @ Q + b2 + x )   Bt = Qt [128][384]
// ---------------------------------------------------------------------------
__global__ __launch_bounds__(256)
void k_mm2_ln(const unsigned short* __restrict__ A, const unsigned short* __restrict__ Bt,
              const float* __restrict__ bias, const float* __restrict__ xres,
              const float* __restrict__ lng, const float* __restrict__ lnb,
              float* __restrict__ out)
{
    __shared__ char lds[24576]; // As [0,8192), Bs [8192,24576)
    const int bm = blockIdx.x * 64;
    const int tid = threadIdx.x, w = tid >> 6, lane = tid & 63;
    const int lrow = lane & 15, lk = lane >> 4;
    const short z0 = 0;
    f32x4 acc[8];
    #pragma unroll
    for (int f = 0; f < 8; ++f) { acc[f][0]=0.f; acc[f][1]=0.f; acc[f][2]=0.f; acc[f][3]=0.f; }

    for (int k0 = 0; k0 < 384; k0 += 64) {
        #pragma unroll
        for (int it = 0; it < 2; ++it) {
            int c = tid + it * 256;
            int row = c >> 3, o = c & 7;
            int grow = bm + row;
            bf16x8 v = {z0,z0,z0,z0,z0,z0,z0,z0};
            if (grow < M_NODES) v = *(const bf16x8*)(A + (size_t)grow * 384 + k0 + o * 8);
            int b = (row * 128 + o * 16) ^ ((row & 7) << 4);
            *(bf16x8*)(lds + b) = v;
        }
        #pragma unroll
        for (int it = 0; it < 4; ++it) {
            int c = tid + it * 256;
            int row = c >> 3, o = c & 7;   // row 0..127
            bf16x8 v = *(const bf16x8*)(Bt + (size_t)row * 384 + k0 + o * 8);
            int b = 8192 + ((row * 128 + o * 16) ^ ((row & 7) << 4));
            *(bf16x8*)(lds + b) = v;
        }
        __syncthreads();
        #pragma unroll
        for (int kk = 0; kk < 2; ++kk) {
            int ar = w * 16 + lrow;
            bf16x8 a = *(const bf16x8*)(lds + ((ar * 128 + kk * 64 + lk * 16) ^ ((lrow & 7) << 4)));
            #pragma unroll
            for (int f = 0; f < 8; ++f) {
                int br = 16 * f + lrow;
                bf16x8 bb = *(const bf16x8*)(lds + 8192 + ((br * 128 + kk * 64 + lk * 16) ^ ((lrow & 7) << 4)));
                acc[f] = __builtin_amdgcn_mfma_f32_16x16x32_bf16(a, bb, acc[f], 0, 0, 0);
            }
        }
        __syncthreads();
    }

    // fused bias + residual + LayerNorm epilogue
    int cols[8]; float bs[8], gg[8], bbv[8];
    #pragma unroll
    for (int f = 0; f < 8; ++f) {
        cols[f] = 16 * f + lrow;
        bs[f] = bias[cols[f]];
        gg[f] = lng[cols[f]];
        bbv[f] = lnb[cols[f]];
    }
    #pragma unroll
    for (int rg = 0; rg < 4; ++rg) {
        int grow = bm + w * 16 + lk * 4 + rg;
        bool ok = grow < M_NODES;
        float h[8];
        float s = 0.f;
        #pragma unroll
        for (int f = 0; f < 8; ++f) {
            float hv = 0.f;
            if (ok) hv = acc[f][rg] + bs[f] + xres[(size_t)grow * 128 + cols[f]];
            h[f] = hv;
            s += hv;
        }
        #pragma unroll
        for (int m = 1; m < 16; m <<= 1) s += __shfl_xor(s, m);
        float mu = s * (1.0f / 128.0f);
        float vv = 0.f;
        #pragma unroll
        for (int f = 0; f < 8; ++f) { float d = h[f] - mu; vv += d * d; }
        #pragma unroll
        for (int m = 1; m < 16; m <<= 1) vv += __shfl_xor(vv, m);
        float rs = rsqrtf(vv * (1.0f / 128.0f) + LN_EPS);
        if (ok) {
            #pragma unroll
            for (int f = 0; f < 8; ++f)
                out[(size_t)grow * 128 + cols[f]] = (h[f] - mu) * rs * gg[f] + bbv[f];
        }
    }
}

// ---------------------------------------------------------------------------
extern "C" void kernel_launch(void* const* d_in, const int* in_sizes, int n_in,
                              void* d_out, int out_size, void* d_ws, size_t ws_size,
                              hipStream_t stream)
{
    const float* x    = (const float*)d_in[0];
    const int*   ei   = (const int*)  d_in[1];
    const float* ea   = (const float*)d_in[2];
    const float* W    = (const float*)d_in[3];
    const float* Wed  = (const float*)d_in[4];
    const float* asv  = (const float*)d_in[5];
    const float* adv  = (const float*)d_in[6];
    const float* aev  = (const float*)d_in[7];
    const float* gb   = (const float*)d_in[8];
    const float* lw   = (const float*)d_in[9];
    const float* lb   = (const float*)d_in[10];
    const float* lng  = (const float*)d_in[11];
    const float* lnb  = (const float*)d_in[12];
    float* out = (float*)d_out;

    char* wsp = (char*)d_ws;
    size_t off = 0;
    auto alloc = [&](size_t bytes) -> void* {
        void* p = wsp + off;
        off += bytes;
        off = (off + 255) & ~(size_t)255;
        return p;
    };

    // zero-init region (must be contiguous at start)
    int*   deg     = (int*)  alloc((size_t)M_NODES * 4);
    int*   cursor  = (int*)  alloc((size_t)M_NODES * 4);
    size_t zero_bytes = off;
    float* small   = (float*)alloc(816 * 4);
    float* b2      = (float*)alloc(128 * 4);
    float* asrc    = (float*)alloc((size_t)M_NODES * 3 * 4);
    float* adst    = (float*)alloc((size_t)M_NODES * 3 * 4);
    int*   offs    = (int*)  alloc((size_t)(M_NODES + 1) * 4);
    float* aebuf   = (float*)alloc((size_t)NE * 3 * 4);
    float4* edata  = (float4*)alloc((size_t)NE * 32);
    unsigned short* x16   = (unsigned short*)alloc((size_t)M_NODES * IN_F * 2);
    unsigned short* Qt16  = (unsigned short*)alloc((size_t)OUT_F * HO * 2);
    unsigned short* sbar  = (unsigned short*)alloc((size_t)M_NODES * HO * 2);
    (void)ws_size; (void)in_sizes; (void)n_in; (void)out_size;

    hipMemsetAsync(d_ws, 0, zero_bytes, stream);

    k_small<<<1, 448, 0, stream>>>(W, Wed, asv, adv, aev, small);
    k_prep_q<<<HO, 128, 0, stream>>>(W, lw, Qt16);
    k_bias2<<<1, 128, 0, stream>>>(gb, lw, lb, b2);
    k_attn_node<<<(M_NODES + 3) / 4, 256, 0, stream>>>(x, small, asrc, adst, x16);
    k_ae<<<(NE + 255) / 256, 256, 0, stream>>>(ei, ea, small, aebuf, deg);
    k_scan<<<1, 1024, 0, stream>>>(deg, offs, M_NODES);
    k_fill<<<(NE + 255) / 256, 256, 0, stream>>>(ei, aebuf, asrc, offs, cursor, edata);
    k_agg<<<M_NODES, 128, 0, stream>>>(offs, edata, asrc, adst, x16, sbar);
    k_mm2_ln<<<(M_NODES + 63) / 64, 256, 0, stream>>>(sbar, Qt16, b2, x, lng, lnb, out);
}

// Round 4
// 248.849 us; speedup vs baseline: 2.8679x; 1.3295x over previous
//
#include <hip/hip_runtime.h>
#include <hip/hip_bf16.h>
#include <math.h>

#define M_NODES 50000
#define IN_F    128
#define OUT_F   128
#define NH      3
#define ED_F    16
#define NE      800000
#define HO      (NH * OUT_F)   // 384
#define NEG_SLOPE 0.2f
#define LN_EPS    1e-5f
#define SCAN_B  1024
#define NBLK    ((M_NODES + SCAN_B - 1) / SCAN_B)   // 49

typedef __attribute__((ext_vector_type(8))) short bf16x8;
typedef __attribute__((ext_vector_type(4))) float f32x4;

__device__ __forceinline__ float b2f(unsigned short u) {
    unsigned int x = ((unsigned int)u) << 16;
    return __uint_as_float(x);
}
__device__ __forceinline__ unsigned short f2b(float f) {
    __hip_bfloat16 h = __float2bfloat16(f);
    return *(unsigned short*)&h;
}

// ---------------------------------------------------------------------------
// K2: tiny precompute of folded attention vectors
// small: [0,384) Wa_src(k*3+h) | [384,768) Wa_dst | [768,816) We(d*3+h)
// ---------------------------------------------------------------------------
__global__ void k_small(const float* __restrict__ W, const float* __restrict__ Wed,
                        const float* __restrict__ a_s, const float* __restrict__ a_d,
                        const float* __restrict__ a_e, float* __restrict__ small)
{
    int t = threadIdx.x;
    if (t < 384) {
        int k = t / 3, h = t - k * 3;
        float s1 = 0.f, s2 = 0.f;
        for (int c = 0; c < OUT_F; ++c) {
            float w = W[k * HO + h * OUT_F + c];
            s1 += w * a_s[h * OUT_F + c];
            s2 += w * a_d[h * OUT_F + c];
        }
        small[t] = s1;
        small[384 + t] = s2;
    } else if (t < 384 + 48) {
        int u = t - 384; int d = u / 3, h = u - d * 3;
        float s = 0.f;
        for (int c = 0; c < OUT_F; ++c)
            s += Wed[d * HO + h * OUT_F + c] * a_e[h * OUT_F + c];
        small[768 + u] = s;
    }
}

// ---------------------------------------------------------------------------
// Kq: Q[h*128+t, j] = sum_c W[t, h*128+c] * lw[h*128+c, j]
// stored transposed bf16: Qt[j*384 + h*128+t].  grid=384 blocks, 128 thr
// ---------------------------------------------------------------------------
__global__ void k_prep_q(const float* __restrict__ W, const float* __restrict__ lw,
                         unsigned short* __restrict__ Qt)
{
    int i = blockIdx.x;           // h*128 + t
    int h = i >> 7, t = i & 127;
    int j = threadIdx.x;
    float s = 0.f;
    const float* wrow = W + (size_t)t * HO + h * 128;
    const float* lcol = lw + (size_t)(h * 128) * 128 + j;
    #pragma unroll 4
    for (int c = 0; c < 128; ++c)
        s += wrow[c] * lcol[(size_t)c * 128];
    Qt[(size_t)j * HO + i] = f2b(s);
}

// b2[j] = lb[j] + sum_i gb[i]*lw[i*128+j]   (1 block, 128 thr)
__global__ void k_bias2(const float* __restrict__ gb, const float* __restrict__ lw,
                        const float* __restrict__ lb, float* __restrict__ b2)
{
    int j = threadIdx.x;
    float s = lb[j];
    for (int i = 0; i < HO; ++i)
        s += gb[i] * lw[(size_t)i * 128 + j];
    b2[j] = s;
}

// ---------------------------------------------------------------------------
// K3: fused: asrc/adst (fp32 reduce, padded float4) + x -> bf16 cast
// ---------------------------------------------------------------------------
__global__ void k_attn_node(const float* __restrict__ x, const float* __restrict__ small,
                            float4* __restrict__ asrc4, float4* __restrict__ adst4,
                            unsigned short* __restrict__ x16)
{
    int n = blockIdx.x * 4 + (threadIdx.x >> 6);
    int l = threadIdx.x & 63;
    if (n >= M_NODES) return;
    float x0 = x[(size_t)n * IN_F + l];
    float x1 = x[(size_t)n * IN_F + 64 + l];
    x16[(size_t)n * IN_F + l]      = f2b(x0);
    x16[(size_t)n * IN_F + 64 + l] = f2b(x1);
    float ph[3], qh[3];
    #pragma unroll
    for (int h = 0; h < 3; ++h) {
        float p = x0 * small[l * 3 + h]        + x1 * small[(64 + l) * 3 + h];
        float q = x0 * small[384 + l * 3 + h]  + x1 * small[384 + (64 + l) * 3 + h];
        #pragma unroll
        for (int s = 32; s; s >>= 1) { p += __shfl_xor(p, s); q += __shfl_xor(q, s); }
        ph[h] = p; qh[h] = q;
    }
    if (l == 0) {
        asrc4[n] = make_float4(ph[0], ph[1], ph[2], 0.f);
        adst4[n] = make_float4(qh[0], qh[1], qh[2], 0.f);
    }
}

// ---------------------------------------------------------------------------
// K_deg: degree count (one atomic per edge)
// ---------------------------------------------------------------------------
__global__ void k_deg(const int* __restrict__ ei, int* __restrict__ deg)
{
    int e = blockIdx.x * blockDim.x + threadIdx.x;
    if (e >= NE) return;
    atomicAdd(&deg[ei[NE + e]], 1);
}

// ---------------------------------------------------------------------------
// 3-phase multi-block exclusive scan of deg -> offs
// ---------------------------------------------------------------------------
__global__ void k_scan_sum(const int* __restrict__ deg, int* __restrict__ bsum)
{
    __shared__ int ws[16];
    int b = blockIdx.x, t = threadIdx.x;
    int i = b * SCAN_B + t;
    int v = (i < M_NODES) ? deg[i] : 0;
    #pragma unroll
    for (int s = 32; s; s >>= 1) v += __shfl_xor(v, s);
    int w = t >> 6, lane = t & 63;
    if (lane == 0) ws[w] = v;
    __syncthreads();
    if (t == 0) {
        int s = 0;
        #pragma unroll
        for (int k = 0; k < 16; ++k) s += ws[k];
        bsum[b] = s;
    }
}

__global__ void k_scan_top(const int* __restrict__ bsum, int* __restrict__ bpre)
{
    int t = threadIdx.x;
    int v = (t < NBLK) ? bsum[t] : 0;
    int x = v;
    #pragma unroll
    for (int s = 1; s < 64; s <<= 1) {
        int u = __shfl_up(x, s);
        if (t >= s) x += u;
    }
    if (t < NBLK) bpre[t] = x - v;
}

__global__ void k_scan_local(const int* __restrict__ deg, const int* __restrict__ bpre,
                             int* __restrict__ offs)
{
    __shared__ int ws[16];
    int b = blockIdx.x, t = threadIdx.x;
    int i = b * SCAN_B + t;
    int v = (i < M_NODES) ? deg[i] : 0;
    int x = v;
    int lane = t & 63, w = t >> 6;
    #pragma unroll
    for (int s = 1; s < 64; s <<= 1) {
        int u = __shfl_up(x, s);
        if (lane >= s) x += u;
    }
    if (lane == 63) ws[w] = x;
    __syncthreads();
    if (w == 0) {
        int tt = (lane < 16) ? ws[lane] : 0;
        #pragma unroll
        for (int s = 1; s < 16; s <<= 1) {
            int u = __shfl_up(tt, s);
            if (lane >= s) tt += u;
        }
        if (lane < 16) ws[lane] = tt;
    }
    __syncthreads();
    int incl = x + ((w > 0) ? ws[w - 1] : 0) + bpre[b];
    if (i < M_NODES) offs[i + 1] = incl;
    if (i == 0) offs[0] = 0;
}

// ---------------------------------------------------------------------------
// K_fill: fused ae compute + CSR fill, 32B records {r, ae0..2 | asrc(r)0..2, 0}
// ---------------------------------------------------------------------------
__global__ void k_fill(const int* __restrict__ ei, const float* __restrict__ ea,
                       const float* __restrict__ small, const float4* __restrict__ asrc4,
                       const int* __restrict__ offs, int* __restrict__ cursor,
                       float4* __restrict__ edata)
{
    int e = blockIdx.x * blockDim.x + threadIdx.x;
    if (e >= NE) return;
    int r = ei[e], c = ei[NE + e];
    const float4* p = (const float4*)(ea + (size_t)e * 16);
    float4 q0 = p[0], q1 = p[1], q2 = p[2], q3 = p[3];
    float v[16] = {q0.x,q0.y,q0.z,q0.w, q1.x,q1.y,q1.z,q1.w,
                   q2.x,q2.y,q2.z,q2.w, q3.x,q3.y,q3.z,q3.w};
    const float* Wev = small + 768;
    float ae[3];
    #pragma unroll
    for (int h = 0; h < 3; ++h) {
        float s = 0.f;
        #pragma unroll
        for (int d = 0; d < 16; ++d) s += v[d] * Wev[d * 3 + h];
        ae[h] = s;
    }
    float4 as = asrc4[r];
    int pos = atomicAdd(&cursor[c], 1);
    size_t o = (size_t)(offs[c] + pos) * 2;
    edata[o]     = make_float4(__int_as_float(r), ae[0], ae[1], ae[2]);
    edata[o + 1] = make_float4(as.x, as.y, as.z, 0.f);
}

// ---------------------------------------------------------------------------
// K_agg v2: two-phase per chunk of <=128 edges.
// Phase A: lane i computes edge i's softmax weight once -> LDS float4 {w,r}.
// Phase B: all lanes broadcast-read LDS, gather x16 row, 3 FMAs.
// Denominators + ae-sums reduced across lanes at the end; self-loop analytic.
// ---------------------------------------------------------------------------
__global__ __launch_bounds__(128)
void k_agg(const int* __restrict__ offs, const float4* __restrict__ edata,
           const float4* __restrict__ asrc4, const float4* __restrict__ adst4,
           const unsigned short* __restrict__ x16, unsigned short* __restrict__ sbar)
{
    __shared__ float4 wsh[128];
    __shared__ float red[6][2];
    int n = blockIdx.x;
    int t = threadIdx.x;
    int off = offs[n], ne = offs[n + 1] - off;
    float4 ad = adst4[n];

    float s0 = 0.f, s1 = 0.f, s2 = 0.f;
    float pd0 = 0.f, pd1 = 0.f, pd2 = 0.f;
    float pa0 = 0.f, pa1 = 0.f, pa2 = 0.f;

    for (int base = 0; base < ne; base += 128) {
        int rem = ne - base;
        int cnt = rem < 128 ? rem : 128;
        __syncthreads();
        if (t < cnt) {
            float4 m0 = edata[(size_t)(off + base + t) * 2];
            float4 m1 = edata[(size_t)(off + base + t) * 2 + 1];
            float al0 = m1.x + ad.x + m0.y;
            float al1 = m1.y + ad.y + m0.z;
            float al2 = m1.z + ad.z + m0.w;
            al0 = (al0 >= 0.f) ? al0 : NEG_SLOPE * al0;
            al1 = (al1 >= 0.f) ? al1 : NEG_SLOPE * al1;
            al2 = (al2 >= 0.f) ? al2 : NEG_SLOPE * al2;
            float w0 = __expf(al0), w1 = __expf(al1), w2 = __expf(al2);
            pa0 += m0.y; pa1 += m0.z; pa2 += m0.w;
            pd0 += w0; pd1 += w1; pd2 += w2;
            wsh[t] = make_float4(w0, w1, w2, m0.x);
        }
        __syncthreads();
        for (int i = 0; i < cnt; ++i) {
            float4 m = wsh[i];
            int r = __float_as_int(m.w);
            float xv = b2f(x16[(size_t)r * IN_F + t]);
            s0 += m.x * xv; s1 += m.y * xv; s2 += m.z * xv;
        }
    }

    // block-reduce pd*, pa* over 128 threads
    #pragma unroll
    for (int s = 32; s; s >>= 1) {
        pd0 += __shfl_xor(pd0, s); pd1 += __shfl_xor(pd1, s); pd2 += __shfl_xor(pd2, s);
        pa0 += __shfl_xor(pa0, s); pa1 += __shfl_xor(pa1, s); pa2 += __shfl_xor(pa2, s);
    }
    int w = t >> 6, lane = t & 63;
    if (lane == 0) {
        red[0][w] = pd0; red[1][w] = pd1; red[2][w] = pd2;
        red[3][w] = pa0; red[4][w] = pa1; red[5][w] = pa2;
    }
    __syncthreads();
    float d0 = red[0][0] + red[0][1];
    float d1 = red[1][0] + red[1][1];
    float d2 = red[2][0] + red[2][1];
    float sa0 = red[3][0] + red[3][1];
    float sa1 = red[4][0] + red[4][1];
    float sa2 = red[5][0] + red[5][1];

    // self-loop: attr = mean of incoming -> ae_loop = mean of ae
    float4 as = asrc4[n];
    float inv = 1.0f / fmaxf((float)ne, 1.0f);
    float al0 = as.x + ad.x + sa0 * inv;
    float al1 = as.y + ad.y + sa1 * inv;
    float al2 = as.z + ad.z + sa2 * inv;
    al0 = (al0 >= 0.f) ? al0 : NEG_SLOPE * al0;
    al1 = (al1 >= 0.f) ? al1 : NEG_SLOPE * al1;
    al2 = (al2 >= 0.f) ? al2 : NEG_SLOPE * al2;
    float w0 = __expf(al0), w1 = __expf(al1), w2 = __expf(al2);
    float xv = b2f(x16[(size_t)n * IN_F + t]);
    s0 += w0 * xv; s1 += w1 * xv; s2 += w2 * xv;
    d0 += w0; d1 += w1; d2 += w2;

    size_t b = (size_t)n * HO;
    sbar[b + t]       = f2b(s0 / d0);
    sbar[b + 128 + t] = f2b(s1 / d1);
    sbar[b + 256 + t] = f2b(s2 / d2);
}

// ---------------------------------------------------------------------------
// MFMA GEMM + bias + residual + LayerNorm fused:
// out[M][128] = LN( sbar[M][384] @ Q + b2 + x )   Bt = Qt [128][384]
// ---------------------------------------------------------------------------
__global__ __launch_bounds__(256)
void k_mm2_ln(const unsigned short* __restrict__ A, const unsigned short* __restrict__ Bt,
              const float* __restrict__ bias, const float* __restrict__ xres,
              const float* __restrict__ lng, const float* __restrict__ lnb,
              float* __restrict__ out)
{
    __shared__ char lds[24576]; // As [0,8192), Bs [8192,24576)
    const int bm = blockIdx.x * 64;
    const int tid = threadIdx.x, w = tid >> 6, lane = tid & 63;
    const int lrow = lane & 15, lk = lane >> 4;
    const short z0 = 0;
    f32x4 acc[8];
    #pragma unroll
    for (int f = 0; f < 8; ++f) { acc[f][0]=0.f; acc[f][1]=0.f; acc[f][2]=0.f; acc[f][3]=0.f; }

    for (int k0 = 0; k0 < 384; k0 += 64) {
        #pragma unroll
        for (int it = 0; it < 2; ++it) {
            int c = tid + it * 256;
            int row = c >> 3, o = c & 7;
            int grow = bm + row;
            bf16x8 v = {z0,z0,z0,z0,z0,z0,z0,z0};
            if (grow < M_NODES) v = *(const bf16x8*)(A + (size_t)grow * 384 + k0 + o * 8);
            int b = (row * 128 + o * 16) ^ ((row & 7) << 4);
            *(bf16x8*)(lds + b) = v;
        }
        #pragma unroll
        for (int it = 0; it < 4; ++it) {
            int c = tid + it * 256;
            int row = c >> 3, o = c & 7;   // row 0..127
            bf16x8 v = *(const bf16x8*)(Bt + (size_t)row * 384 + k0 + o * 8);
            int b = 8192 + ((row * 128 + o * 16) ^ ((row & 7) << 4));
            *(bf16x8*)(lds + b) = v;
        }
        __syncthreads();
        #pragma unroll
        for (int kk = 0; kk < 2; ++kk) {
            int ar = w * 16 + lrow;
            bf16x8 a = *(const bf16x8*)(lds + ((ar * 128 + kk * 64 + lk * 16) ^ ((lrow & 7) << 4)));
            #pragma unroll
            for (int f = 0; f < 8; ++f) {
                int br = 16 * f + lrow;
                bf16x8 bb = *(const bf16x8*)(lds + 8192 + ((br * 128 + kk * 64 + lk * 16) ^ ((lrow & 7) << 4)));
                acc[f] = __builtin_amdgcn_mfma_f32_16x16x32_bf16(a, bb, acc[f], 0, 0, 0);
            }
        }
        __syncthreads();
    }

    // fused bias + residual + LayerNorm epilogue
    int cols[8]; float bs[8], gg[8], bbv[8];
    #pragma unroll
    for (int f = 0; f < 8; ++f) {
        cols[f] = 16 * f + lrow;
        bs[f] = bias[cols[f]];
        gg[f] = lng[cols[f]];
        bbv[f] = lnb[cols[f]];
    }
    #pragma unroll
    for (int rg = 0; rg < 4; ++rg) {
        int grow = bm + w * 16 + lk * 4 + rg;
        bool ok = grow < M_NODES;
        float h[8];
        float s = 0.f;
        #pragma unroll
        for (int f = 0; f < 8; ++f) {
            float hv = 0.f;
            if (ok) hv = acc[f][rg] + bs[f] + xres[(size_t)grow * 128 + cols[f]];
            h[f] = hv;
            s += hv;
        }
        #pragma unroll
        for (int m = 1; m < 16; m <<= 1) s += __shfl_xor(s, m);
        float mu = s * (1.0f / 128.0f);
        float vv = 0.f;
        #pragma unroll
        for (int f = 0; f < 8; ++f) { float d = h[f] - mu; vv += d * d; }
        #pragma unroll
        for (int m = 1; m < 16; m <<= 1) vv += __shfl_xor(vv, m);
        float rs = rsqrtf(vv * (1.0f / 128.0f) + LN_EPS);
        if (ok) {
            #pragma unroll
            for (int f = 0; f < 8; ++f)
                out[(size_t)grow * 128 + cols[f]] = (h[f] - mu) * rs * gg[f] + bbv[f];
        }
    }
}

// ---------------------------------------------------------------------------
extern "C" void kernel_launch(void* const* d_in, const int* in_sizes, int n_in,
                              void* d_out, int out_size, void* d_ws, size_t ws_size,
                              hipStream_t stream)
{
    const float* x    = (const float*)d_in[0];
    const int*   ei   = (const int*)  d_in[1];
    const float* ea   = (const float*)d_in[2];
    const float* W    = (const float*)d_in[3];
    const float* Wed  = (const float*)d_in[4];
    const float* asv  = (const float*)d_in[5];
    const float* adv  = (const float*)d_in[6];
    const float* aev  = (const float*)d_in[7];
    const float* gb   = (const float*)d_in[8];
    const float* lw   = (const float*)d_in[9];
    const float* lb   = (const float*)d_in[10];
    const float* lng  = (const float*)d_in[11];
    const float* lnb  = (const float*)d_in[12];
    float* out = (float*)d_out;

    char* wsp = (char*)d_ws;
    size_t off = 0;
    auto alloc = [&](size_t bytes) -> void* {
        void* p = wsp + off;
        off += bytes;
        off = (off + 255) & ~(size_t)255;
        return p;
    };

    // zero-init region (must be contiguous at start)
    int*   deg     = (int*)  alloc((size_t)M_NODES * 4);
    int*   cursor  = (int*)  alloc((size_t)M_NODES * 4);
    size_t zero_bytes = off;
    float* small   = (float*)alloc(816 * 4);
    float* b2      = (float*)alloc(128 * 4);
    int*   bsum    = (int*)  alloc((size_t)NBLK * 4);
    int*   bpre    = (int*)  alloc((size_t)NBLK * 4);
    float4* asrc4  = (float4*)alloc((size_t)M_NODES * 16);
    float4* adst4  = (float4*)alloc((size_t)M_NODES * 16);
    int*   offs    = (int*)  alloc((size_t)(M_NODES + 1) * 4);
    float4* edata  = (float4*)alloc((size_t)NE * 32);
    unsigned short* x16   = (unsigned short*)alloc((size_t)M_NODES * IN_F * 2);
    unsigned short* Qt16  = (unsigned short*)alloc((size_t)OUT_F * HO * 2);
    unsigned short* sbar  = (unsigned short*)alloc((size_t)M_NODES * HO * 2);
    (void)ws_size; (void)in_sizes; (void)n_in; (void)out_size;

    hipMemsetAsync(d_ws, 0, zero_bytes, stream);

    k_small<<<1, 448, 0, stream>>>(W, Wed, asv, adv, aev, small);
    k_prep_q<<<HO, 128, 0, stream>>>(W, lw, Qt16);
    k_bias2<<<1, 128, 0, stream>>>(gb, lw, lb, b2);
    k_attn_node<<<(M_NODES + 3) / 4, 256, 0, stream>>>(x, small, asrc4, adst4, x16);
    k_deg<<<(NE + 255) / 256, 256, 0, stream>>>(ei, deg);
    k_scan_sum<<<NBLK, SCAN_B, 0, stream>>>(deg, bsum);
    k_scan_top<<<1, 64, 0, stream>>>(bsum, bpre);
    k_scan_local<<<NBLK, SCAN_B, 0, stream>>>(deg, bpre, offs);
    k_fill<<<(NE + 255) / 256, 256, 0, stream>>>(ei, ea, small, asrc4, offs, cursor, edata);
    k_agg<<<M_NODES, 128, 0, stream>>>(offs, edata, asrc4, adst4, x16, sbar);
    k_mm2_ln<<<(M_NODES + 63) / 64, 256, 0, stream>>>(sbar, Qt16, b2, x, lng, lnb, out);
}